// Round 2
// baseline (245.503 us; speedup 1.0000x reference)
//
#include <hip/hip_runtime.h>

typedef _Float16 half8 __attribute__((ext_vector_type(8)));
typedef _Float16 half2v __attribute__((ext_vector_type(2)));
typedef float float4v __attribute__((ext_vector_type(4)));

// ---- helpers ----
__device__ __forceinline__ float dot2acc(unsigned a, unsigned b, float c) {
#if __has_builtin(__builtin_amdgcn_fdot2)
  return __builtin_amdgcn_fdot2(__builtin_bit_cast(half2v, a), __builtin_bit_cast(half2v, b), c, false);
#else
  half2v ha = __builtin_bit_cast(half2v, a);
  half2v hb = __builtin_bit_cast(half2v, b);
  c += (float)ha[0] * (float)hb[0];
  c += (float)ha[1] * (float)hb[1];
  return c;
#endif
}
__device__ __forceinline__ unsigned hscale(unsigned a, float s) {
  half2v ha = __builtin_bit_cast(half2v, a);
  half2v r;
  r[0] = (_Float16)((float)ha[0] * s);
  r[1] = (_Float16)((float)ha[1] * s);
  return __builtin_bit_cast(unsigned, r);
}
__device__ __forceinline__ unsigned pack2(float a, float b) {
  half2v h;
  h[0] = (_Float16)a;
  h[1] = (_Float16)b;
  return __builtin_bit_cast(unsigned, h);
}
__device__ __forceinline__ void gload_lds16(const void* g, void* l) {
  __builtin_amdgcn_global_load_lds((const __attribute__((address_space(1))) unsigned*)g,
                                   (__attribute__((address_space(3))) unsigned*)l, 16, 0, 0);
}

// ---- fp32 -> fp16 convert, all three tensors in one launch ----
__global__ void cvt_all(const float4* __restrict__ x, const float4* __restrict__ wqk,
                        const float4* __restrict__ wpj,
                        ushort4* __restrict__ x16, ushort4* __restrict__ wqk16,
                        ushort4* __restrict__ wpj16) {
  int b = blockIdx.x;
  const float4* s;
  ushort4* d;
  int i;
  if (b < 16384) { s = x; d = x16; i = b * 256 + threadIdx.x; }
  else if (b < 16512) { s = wqk; d = wqk16; i = (b - 16384) * 256 + threadIdx.x; }
  else { s = wpj; d = wpj16; i = (b - 16512) * 256 + threadIdx.x; }
  float4 v = s[i];
  _Float16 a = (_Float16)v.x, bb = (_Float16)v.y, c = (_Float16)v.z, e = (_Float16)v.w;
  ushort4 o;
  o.x = __builtin_bit_cast(unsigned short, a);
  o.y = __builtin_bit_cast(unsigned short, bb);
  o.z = __builtin_bit_cast(unsigned short, c);
  o.w = __builtin_bit_cast(unsigned short, e);
  d[i] = o;
}

// ---- GEMM1: qk = x16 @ wqk16^T, epilogue scatters to q16/k16 (b,h,t,yx,j) fp16 ----
__global__ __launch_bounds__(256, 2)
void gemm_qk(const _Float16* __restrict__ A, const _Float16* __restrict__ Bw,
             _Float16* __restrict__ qo, _Float16* __restrict__ ko) {
  __shared__ _Float16 Ash[4096];
  __shared__ _Float16 Bsh[4096];
  const int tid = threadIdx.x;
  const int lane = tid & 63, w = tid >> 6;
  const int wm = w >> 1, wn = w & 1;
  const int ml = lane & 15, qd = lane >> 4;
  const int m0 = blockIdx.y * 128, n0 = blockIdx.x * 128;

  float4v acc[4][4];
  float4v z = {0.f, 0.f, 0.f, 0.f};
#pragma unroll
  for (int i = 0; i < 4; ++i)
#pragma unroll
    for (int j = 0; j < 4; ++j) acc[i][j] = z;

  const _Float16* Ap = A + (size_t)m0 * 256;
  const _Float16* Bp = Bw + (size_t)n0 * 256;
  const int gr = w * 64 + lane;
  const int row0 = gr >> 2, kb = gr & 3;

  for (int kt = 0; kt < 8; ++kt) {
    int k0 = kt * 32;
    gload_lds16(Ap + row0 * 256 + k0 + kb * 8, Ash + (size_t)(w * 64) * 8);
    gload_lds16(Ap + (row0 + 64) * 256 + k0 + kb * 8, Ash + (size_t)(256 + w * 64) * 8);
    gload_lds16(Bp + row0 * 256 + k0 + kb * 8, Bsh + (size_t)(w * 64) * 8);
    gload_lds16(Bp + (row0 + 64) * 256 + k0 + kb * 8, Bsh + (size_t)(256 + w * 64) * 8);
    __syncthreads();
    half8 af[4], bf[4];
#pragma unroll
    for (int im = 0; im < 4; ++im) {
      af[im] = *(const half8*)(Ash + (wm * 64 + im * 16 + ml) * 32 + qd * 8);
      bf[im] = *(const half8*)(Bsh + (wn * 64 + im * 16 + ml) * 32 + qd * 8);
    }
#pragma unroll
    for (int im = 0; im < 4; ++im)
#pragma unroll
      for (int in = 0; in < 4; ++in)
        acc[im][in] = __builtin_amdgcn_mfma_f32_16x16x32_f16(af[im], bf[in], acc[im][in], 0, 0, 0);
    __syncthreads();
  }

#pragma unroll
  for (int im = 0; im < 4; ++im) {
    int rowr0 = m0 + wm * 64 + im * 16 + qd * 4;
#pragma unroll
    for (int in = 0; in < 4; ++in) {
      int col = n0 + wn * 64 + in * 16 + ml;
      int s = col >> 8, h = (col >> 5) & 7, j = col & 31;
      _Float16* dst = s ? ko : qo;
#pragma unroll
      for (int r = 0; r < 4; ++r) {
        int rowr = rowr0 + r;
        int b = rowr >> 13, n = rowr & 8191;
        int t = n >> 10, yx = n & 1023;
        int p = b * 64 + h * 8 + t;
        dst[((size_t)p * 1024 + yx) * 32 + j] = (_Float16)acc[im][in][r];
      }
    }
  }
}

// ---- correlation via swapped-operand banded MFMA ----
// grid: 512 volumes * 4 tiles of 16x16; block 256 (4 waves); LDS 74240B -> 2 blocks/CU.
// corr matrix: [posC=16*x+y][dy 0..7][slot 0..15] fp16, pitch 136 halfs.
//   slot = kcol - 8*(x>=8); physical dy' = dy ^ (x&7); slot ^= 8*(x>>3).
// Band phase: D'[kcol][x] = mfma(K_row, Q_row); lane's 4 regs = 4 consecutive kcol,
//   same x -> one aligned ds_write_b64 per nt'. K,Q from GLOBAL, shfl-normalized in reg.
// Epilogue: v^T[d][pos] = W[32d][64kappa] x corr^T per x-class; per-pos dx-shift is a
//   wave-uniform address offset + uniform 16-bit funnel. Output via small LDS transpose.
__global__ __launch_bounds__(256, 2)
void corr_kernel(const _Float16* __restrict__ q16, const _Float16* __restrict__ k16,
                 const float* __restrict__ wcorr, const float* __restrict__ bcorr,
                 _Float16* __restrict__ outp) {
  __shared__ __align__(16) _Float16 S[37120];
  _Float16* corr = S;           // 256*136 = 34816 halfs
  _Float16* wch = S + 34816;    // [32 d][72] kappa = dy*8+dx (pad zeros)

  const int tid = threadIdx.x;
  const int bx = blockIdx.x;
  const int p = bx >> 2, tile = bx & 3;
  const int y0 = (tile >> 1) * 16, x0 = (tile & 1) * 16;
  const int b = p >> 6, h = (p >> 3) & 7, t = p & 7;
  const int pk = (t < 7) ? p + 1 : p;
  const int lane = tid & 63, w = tid >> 6;
  const int ml = lane & 15, qd = lane >> 4;

  // ---- stage w_corr as [d][72], kappa = dy*8+dx, zero outside 7x7 ----
  {
    int d = tid >> 3, c8 = tid & 7;
#pragma unroll
    for (int i = 0; i < 9; ++i) {
      int kp = c8 * 9 + i;
      int dy = kp >> 3, dx = kp & 7;
      float v = (dy < 7 && dx < 7) ? wcorr[d * 49 + dy * 7 + dx] : 0.f;
      wch[d * 72 + kp] = (_Float16)v;
    }
  }
  // ---- zero logical dy=7 rows (read as K-pad by epilogue, weight 0) ----
  {
    int dyp = 7 ^ ((tid >> 4) & 7);
    *(uint4*)(corr + tid * 136 + dyp * 16) = make_uint4(0u, 0u, 0u, 0u);
    *(uint4*)(corr + tid * 136 + dyp * 16 + 8) = make_uint4(0u, 0u, 0u, 0u);
  }

  // ---- Q B-fragments: rows y = 4w..4w+3, normalized in-register ----
  const _Float16* qbase = q16 + (size_t)p * 32768;
  half8 qB[4];
#pragma unroll
  for (int yi = 0; yi < 4; ++yi) {
    int y = 4 * w + yi;
    qB[yi] = *(const half8*)(qbase + (size_t)((y0 + y) * 32 + (x0 + ml)) * 32 + qd * 8);
    unsigned* u = (unsigned*)&qB[yi];
    float ss = 0.f;
#pragma unroll
    for (int e = 0; e < 4; ++e) ss = dot2acc(u[e], u[e], ss);
    ss += __shfl_xor(ss, 16);
    ss += __shfl_xor(ss, 32);
    float sc = 1.f / fmaxf(sqrtf(ss), 1e-12f);
#pragma unroll
    for (int e = 0; e < 4; ++e) u[e] = hscale(u[e], sc);
  }

  // ---- band loop: wave w owns q rows 4w..4w+3; k rows kr = 4w-3 .. 4w+6 ----
  const _Float16* kbase = k16 + (size_t)pk * 32768;
  const float4v zf = {0.f, 0.f, 0.f, 0.f};
  const int gxa = x0 + ml - 3;          // kcol = ml
  const int gxb = gxa + 16;             // kcol = 16+ml
  const int cxa = min(max(gxa, 0), 31);
  const int cxb = min(gxb, 31);
  const bool vca = (gxa >= 0) && (gxa < 32);
  const bool vcb = (gxb < 32);
  const int sx8 = (ml >> 3) << 3;
  const bool v0 = (ml < 8) || (qd >= 2);
  const bool v1 = (ml >= 8) && (qd < 2);
  const int off0 = ((4 * qd) - ((ml >= 8) ? 8 : 0)) ^ sx8;  // slot base, nt'=0
  const int off1 = (8 + 4 * qd) ^ sx8;                      // slot base, nt'=1

#pragma unroll
  for (int kri = 0; kri < 10; ++kri) {
    int kr = 4 * w - 3 + kri;
    int gy = y0 + kr;
    half8 ka0 = {}, kb0 = {};
    if (gy >= 0 && gy < 32) {
      ka0 = *(const half8*)(kbase + (size_t)(gy * 32 + cxa) * 32 + qd * 8);
      kb0 = *(const half8*)(kbase + (size_t)(gy * 32 + cxb) * 32 + qd * 8);
      {
        unsigned* u = (unsigned*)&ka0;
        float ss = 0.f;
#pragma unroll
        for (int e = 0; e < 4; ++e) ss = dot2acc(u[e], u[e], ss);
        ss += __shfl_xor(ss, 16);
        ss += __shfl_xor(ss, 32);
        float sc = vca ? 1.f / fmaxf(sqrtf(ss), 1e-12f) : 0.f;
#pragma unroll
        for (int e = 0; e < 4; ++e) u[e] = hscale(u[e], sc);
      }
      {
        unsigned* u = (unsigned*)&kb0;
        float ss = 0.f;
#pragma unroll
        for (int e = 0; e < 4; ++e) ss = dot2acc(u[e], u[e], ss);
        ss += __shfl_xor(ss, 16);
        ss += __shfl_xor(ss, 32);
        float sc = vcb ? 1.f / fmaxf(sqrtf(ss), 1e-12f) : 0.f;
#pragma unroll
        for (int e = 0; e < 4; ++e) u[e] = hscale(u[e], sc);
      }
    }
#pragma unroll
    for (int yi = 0; yi < 4; ++yi) {
      int dy = kri - yi;
      if (dy < 0 || dy > 6) continue;
      float4v D0 = __builtin_amdgcn_mfma_f32_16x16x32_f16(ka0, qB[yi], zf, 0, 0, 0);
      float4v D1 = __builtin_amdgcn_mfma_f32_16x16x32_f16(kb0, qB[yi], zf, 0, 0, 0);
      int y = 4 * w + yi;
      int base = (16 * ml + y) * 136 + (dy ^ (ml & 7)) * 16;
      if (v0) {
        uint2 pk0;
        pk0.x = pack2(D0[0], D0[1]);
        pk0.y = pack2(D0[2], D0[3]);
        *(uint2*)(corr + base + off0) = pk0;
      }
      if (v1) {
        uint2 pk1;
        pk1.x = pack2(D1[0], D1[1]);
        pk1.y = pack2(D1[2], D1[3]);
        *(uint2*)(corr + base + off1) = pk1;
      }
    }
  }
  __syncthreads();

  // ---- epilogue: v^T[d][pos] per x-class; wave w -> xc = 4w..4w+3 ----
  half8 wA[2][2];
#pragma unroll
  for (int dt = 0; dt < 2; ++dt)
#pragma unroll
    for (int ks = 0; ks < 2; ++ks)
      wA[dt][ks] = *(const half8*)(wch + (dt * 16 + ml) * 72 + ks * 32 + qd * 8);

  float4v vacc[4][2];
#pragma unroll
  for (int i = 0; i < 4; ++i) {
    vacc[i][0] = zf;
    vacc[i][1] = zf;
  }
#pragma unroll
  for (int i = 0; i < 4; ++i) {
    int xc = 4 * w + i;
    int key = xc & 7;             // uniform per wave-iteration
    int x4 = (xc >> 3) << 2;      // dword-index XOR (slot bit3 swizzle)
    int e = key >> 1;
    int sh = key & 1;
#pragma unroll
    for (int ks = 0; ks < 2; ++ks) {
      int dyp = (ks * 4 + qd) ^ key;
      int base = (16 * xc + ml) * 136 + dyp * 16;
      unsigned dw[5];
#pragma unroll
      for (int tt = 0; tt < 5; ++tt)
        dw[tt] = *(const unsigned*)(corr + base + (((e + tt) ^ x4) << 1));
      uint4 bfw;
      if (sh) {
        bfw.x = (dw[0] >> 16) | (dw[1] << 16);
        bfw.y = (dw[1] >> 16) | (dw[2] << 16);
        bfw.z = (dw[2] >> 16) | (dw[3] << 16);
        bfw.w = (dw[3] >> 16) | (dw[4] << 16);
      } else {
        bfw.x = dw[0]; bfw.y = dw[1]; bfw.z = dw[2]; bfw.w = dw[3];
      }
      half8 bfrag = __builtin_bit_cast(half8, bfw);
#pragma unroll
      for (int dt = 0; dt < 2; ++dt)
        vacc[i][dt] = __builtin_amdgcn_mfma_f32_16x16x32_f16(wA[dt][ks], bfrag, vacc[i][dt], 0, 0, 0);
    }
  }
  __syncthreads();

  // ---- transpose through LDS: vout [posN = y*16+x][40], d-block XOR swizzle ----
  _Float16* vout = S;
#pragma unroll
  for (int i = 0; i < 4; ++i) {
    int xc = 4 * w + i;
    int posN = ml * 16 + xc;      // D col ml = y
#pragma unroll
    for (int dt = 0; dt < 2; ++dt) {
      int d0 = dt * 16 + 4 * qd;
      float4 bb = *(const float4*)(bcorr + d0);
      uint2 pkv;
      pkv.x = pack2(vacc[i][dt][0] + bb.x, vacc[i][dt][1] + bb.y);
      pkv.y = pack2(vacc[i][dt][2] + bb.z, vacc[i][dt][3] + bb.w);
      *(uint2*)(vout + posN * 40 + (d0 ^ ((ml & 7) << 2))) = pkv;
    }
  }
  __syncthreads();

  // ---- gather + coalesced 64B global write per thread ----
  {
    int key2 = (tid >> 4) & 7;
    uint2 vv[8];
#pragma unroll
    for (int lb = 0; lb < 8; ++lb)
      vv[lb] = *(const uint2*)(vout + tid * 40 + (((lb ^ key2) << 2)));
    int y = tid >> 4, x = tid & 15;
    int n = t * 1024 + (y0 + y) * 32 + (x0 + x);
    _Float16* dst = outp + (((size_t)(b * 8192 + n)) << 8) + h * 32;
    uint4 o0, o1;
    o0.x = vv[0].x; o0.y = vv[0].y; o0.z = vv[1].x; o0.w = vv[1].y;
    o1.x = vv[2].x; o1.y = vv[2].y; o1.z = vv[3].x; o1.w = vv[3].y;
    *(uint4*)(dst) = o0;
    *(uint4*)(dst + 8) = o1;
    uint4 o2, o3;
    o2.x = vv[4].x; o2.y = vv[4].y; o2.z = vv[5].x; o2.w = vv[5].y;
    o3.x = vv[6].x; o3.y = vv[6].y; o3.z = vv[7].x; o3.w = vv[7].y;
    *(uint4*)(dst + 16) = o2;
    *(uint4*)(dst + 24) = o3;
  }
}

// ---- proj GEMM: out = op16 @ wproj16^T + b_proj (fp32 out) ----
__global__ __launch_bounds__(256, 2)
void gemm_proj(const _Float16* __restrict__ A, const _Float16* __restrict__ Bw,
               const float* __restrict__ bp, float* __restrict__ out) {
  __shared__ _Float16 Ash[4096];
  __shared__ _Float16 Bsh[4096];
  const int tid = threadIdx.x;
  const int lane = tid & 63, w = tid >> 6;
  const int wm = w >> 1, wn = w & 1;
  const int ml = lane & 15, qd = lane >> 4;
  const int m0 = blockIdx.y * 128, n0 = blockIdx.x * 128;

  float4v acc[4][4];
  float4v z = {0.f, 0.f, 0.f, 0.f};
#pragma unroll
  for (int i = 0; i < 4; ++i)
#pragma unroll
    for (int j = 0; j < 4; ++j) acc[i][j] = z;

  const _Float16* Ap = A + (size_t)m0 * 256;
  const _Float16* Bp = Bw + (size_t)n0 * 256;
  const int gr = w * 64 + lane;
  const int row0 = gr >> 2, kb = gr & 3;

  for (int kt = 0; kt < 8; ++kt) {
    int k0 = kt * 32;
    gload_lds16(Ap + row0 * 256 + k0 + kb * 8, Ash + (size_t)(w * 64) * 8);
    gload_lds16(Ap + (row0 + 64) * 256 + k0 + kb * 8, Ash + (size_t)(256 + w * 64) * 8);
    gload_lds16(Bp + row0 * 256 + k0 + kb * 8, Bsh + (size_t)(w * 64) * 8);
    gload_lds16(Bp + (row0 + 64) * 256 + k0 + kb * 8, Bsh + (size_t)(256 + w * 64) * 8);
    __syncthreads();
    half8 af[4], bf[4];
#pragma unroll
    for (int im = 0; im < 4; ++im) {
      af[im] = *(const half8*)(Ash + (wm * 64 + im * 16 + ml) * 32 + qd * 8);
      bf[im] = *(const half8*)(Bsh + (wn * 64 + im * 16 + ml) * 32 + qd * 8);
    }
#pragma unroll
    for (int im = 0; im < 4; ++im)
#pragma unroll
      for (int in = 0; in < 4; ++in)
        acc[im][in] = __builtin_amdgcn_mfma_f32_16x16x32_f16(af[im], bf[in], acc[im][in], 0, 0, 0);
    __syncthreads();
  }

#pragma unroll
  for (int im = 0; im < 4; ++im) {
    int rowr0 = m0 + wm * 64 + im * 16 + qd * 4;
#pragma unroll
    for (int in = 0; in < 4; ++in) {
      int col = n0 + wn * 64 + in * 16 + ml;
      float bias = bp[col];
#pragma unroll
      for (int r = 0; r < 4; ++r)
        out[(size_t)(rowr0 + r) * 256 + col] = acc[im][in][r] + bias;
    }
  }
}

extern "C" void kernel_launch(void* const* d_in, const int* in_sizes, int n_in,
                              void* d_out, int out_size, void* d_ws, size_t ws_size,
                              hipStream_t stream) {
  const float* x      = (const float*)d_in[0];
  const float* w_qk   = (const float*)d_in[1];
  const float* w_corr = (const float*)d_in[2];
  const float* b_corr = (const float*)d_in[3];
  const float* w_proj = (const float*)d_in[4];
  const float* b_proj = (const float*)d_in[5];
  float* out = (float*)d_out;

  char* ws = (char*)d_ws;
  _Float16* x16   = (_Float16*)(ws);
  _Float16* q16   = (_Float16*)(ws + 33554432);
  _Float16* k16   = (_Float16*)(ws + 67108864);
  _Float16* op16  = (_Float16*)(ws + 100663296);
  _Float16* wqk16 = (_Float16*)(ws + 134217728);
  _Float16* wpj16 = (_Float16*)(ws + 134479872);

  cvt_all<<<16576, 256, 0, stream>>>((const float4*)x, (const float4*)w_qk, (const float4*)w_proj,
                                     (ushort4*)x16, (ushort4*)wqk16, (ushort4*)wpj16);
  gemm_qk<<<dim3(4, 512), 256, 0, stream>>>(x16, wqk16, q16, k16);
  corr_kernel<<<2048, 256, 0, stream>>>(q16, k16, w_corr, b_corr, op16);
  gemm_proj<<<dim3(2, 512), 256, 0, stream>>>(op16, wpj16, b_proj, out);
}

// Round 3
// 230.865 us; speedup vs baseline: 1.0634x; 1.0634x over previous
//
#include <hip/hip_runtime.h>

typedef _Float16 half8 __attribute__((ext_vector_type(8)));
typedef _Float16 half2v __attribute__((ext_vector_type(2)));
typedef float float4v __attribute__((ext_vector_type(4)));

// ---- helpers ----
__device__ __forceinline__ float dot2acc(unsigned a, unsigned b, float c) {
#if __has_builtin(__builtin_amdgcn_fdot2)
  return __builtin_amdgcn_fdot2(__builtin_bit_cast(half2v, a), __builtin_bit_cast(half2v, b), c, false);
#else
  half2v ha = __builtin_bit_cast(half2v, a);
  half2v hb = __builtin_bit_cast(half2v, b);
  c += (float)ha[0] * (float)hb[0];
  c += (float)ha[1] * (float)hb[1];
  return c;
#endif
}
__device__ __forceinline__ unsigned hscale(unsigned a, float s) {
  half2v ha = __builtin_bit_cast(half2v, a);
  half2v r;
  r[0] = (_Float16)((float)ha[0] * s);
  r[1] = (_Float16)((float)ha[1] * s);
  return __builtin_bit_cast(unsigned, r);
}
__device__ __forceinline__ unsigned pack2(float a, float b) {
  half2v h;
  h[0] = (_Float16)a;
  h[1] = (_Float16)b;
  return __builtin_bit_cast(unsigned, h);
}
__device__ __forceinline__ void gload_lds16(const void* g, void* l) {
  __builtin_amdgcn_global_load_lds((const __attribute__((address_space(1))) unsigned*)g,
                                   (__attribute__((address_space(3))) unsigned*)l, 16, 0, 0);
}

// ---- fp32 -> fp16 convert, all three tensors in one launch ----
__global__ void cvt_all(const float4* __restrict__ x, const float4* __restrict__ wqk,
                        const float4* __restrict__ wpj,
                        ushort4* __restrict__ x16, ushort4* __restrict__ wqk16,
                        ushort4* __restrict__ wpj16) {
  int b = blockIdx.x;
  const float4* s;
  ushort4* d;
  int i;
  if (b < 16384) { s = x; d = x16; i = b * 256 + threadIdx.x; }
  else if (b < 16512) { s = wqk; d = wqk16; i = (b - 16384) * 256 + threadIdx.x; }
  else { s = wpj; d = wpj16; i = (b - 16512) * 256 + threadIdx.x; }
  float4 v = s[i];
  _Float16 a = (_Float16)v.x, bb = (_Float16)v.y, c = (_Float16)v.z, e = (_Float16)v.w;
  ushort4 o;
  o.x = __builtin_bit_cast(unsigned short, a);
  o.y = __builtin_bit_cast(unsigned short, bb);
  o.z = __builtin_bit_cast(unsigned short, c);
  o.w = __builtin_bit_cast(unsigned short, e);
  d[i] = o;
}

// ---- GEMM1: qk = x16 @ wqk16^T, 2-phase double-buffered staging; swapped-operand
// MFMA so each lane holds 4 consecutive output cols -> packed 8B epilogue stores.
__global__ __launch_bounds__(256, 2)
void gemm_qk(const _Float16* __restrict__ A, const _Float16* __restrict__ Bw,
             _Float16* __restrict__ qo, _Float16* __restrict__ ko) {
  __shared__ _Float16 Ash[8192];  // 2 buffers of 128x32
  __shared__ _Float16 Bsh[8192];
  const int tid = threadIdx.x;
  const int lane = tid & 63, w = tid >> 6;
  const int wm = w >> 1, wn = w & 1;
  const int ml = lane & 15, qd = lane >> 4;
  const int m0 = blockIdx.y * 128, n0 = blockIdx.x * 128;

  float4v acc[4][4];
  float4v z = {0.f, 0.f, 0.f, 0.f};
#pragma unroll
  for (int i = 0; i < 4; ++i)
#pragma unroll
    for (int j = 0; j < 4; ++j) acc[i][j] = z;

  const _Float16* Ap = A + (size_t)m0 * 256;
  const _Float16* Bp = Bw + (size_t)n0 * 256;
  const int gr = w * 64 + lane;
  const int row0 = gr >> 2, kb = gr & 3;

  // prologue: stage kt=0 into buffer 0
  {
    gload_lds16(Ap + row0 * 256 + kb * 8, Ash + (size_t)(w * 64) * 8);
    gload_lds16(Ap + (row0 + 64) * 256 + kb * 8, Ash + (size_t)(256 + w * 64) * 8);
    gload_lds16(Bp + row0 * 256 + kb * 8, Bsh + (size_t)(w * 64) * 8);
    gload_lds16(Bp + (row0 + 64) * 256 + kb * 8, Bsh + (size_t)(256 + w * 64) * 8);
  }
  __syncthreads();

#pragma unroll
  for (int kt = 0; kt < 8; ++kt) {
    const int cur = kt & 1;
    if (kt < 7) {
      const int k0 = (kt + 1) * 32;
      const int nb = (cur ^ 1) * 4096;
      gload_lds16(Ap + row0 * 256 + k0 + kb * 8, Ash + nb + (size_t)(w * 64) * 8);
      gload_lds16(Ap + (row0 + 64) * 256 + k0 + kb * 8, Ash + nb + (size_t)(256 + w * 64) * 8);
      gload_lds16(Bp + row0 * 256 + k0 + kb * 8, Bsh + nb + (size_t)(w * 64) * 8);
      gload_lds16(Bp + (row0 + 64) * 256 + k0 + kb * 8, Bsh + nb + (size_t)(256 + w * 64) * 8);
    }
    const _Float16* Ac = Ash + cur * 4096;
    const _Float16* Bc = Bsh + cur * 4096;
    half8 af[4], bf[4];
#pragma unroll
    for (int im = 0; im < 4; ++im) {
      af[im] = *(const half8*)(Ac + (wm * 64 + im * 16 + ml) * 32 + qd * 8);
      bf[im] = *(const half8*)(Bc + (wn * 64 + im * 16 + ml) * 32 + qd * 8);
    }
#pragma unroll
    for (int im = 0; im < 4; ++im)
#pragma unroll
      for (int in = 0; in < 4; ++in)
        acc[im][in] = __builtin_amdgcn_mfma_f32_16x16x32_f16(bf[in], af[im], acc[im][in], 0, 0, 0);
    __syncthreads();
  }

  // epilogue: D[row n][col m]; lane: row = (base)+ml, cols = base+qd*4..+3 -> 8B store
#pragma unroll
  for (int im = 0; im < 4; ++im) {
    int rowr = m0 + wm * 64 + im * 16 + ml;
    int b = rowr >> 13, n = rowr & 8191;
    int t = n >> 10, yx = n & 1023;
#pragma unroll
    for (int in = 0; in < 4; ++in) {
      int col = n0 + wn * 64 + in * 16 + qd * 4;
      int s = col >> 8, h = (col >> 5) & 7, j = col & 31;
      _Float16* dst = s ? ko : qo;
      int p = b * 64 + h * 8 + t;
      uint2 pk;
      pk.x = pack2(acc[im][in][0], acc[im][in][1]);
      pk.y = pack2(acc[im][in][2], acc[im][in][3]);
      *(uint2*)(dst + ((size_t)p * 1024 + yx) * 32 + j) = pk;
    }
  }
}

// ---- correlation + normalize + (corr @ w_corr^T + b_corr) fused (round-0 version) ----
// grid: 512 volumes * 4 tiles of 16x16; block 256; LDS exactly 40960B -> 4 blocks/CU
__global__ __launch_bounds__(256, 4)
void corr_kernel(const _Float16* __restrict__ q16, const _Float16* __restrict__ k16,
                 const float* __restrict__ wcorr, const float* __restrict__ bcorr,
                 _Float16* __restrict__ outp) {
  __shared__ uint4 smem[2304];  // k-tile (1936 granules) then reused as corr matrix [256][72] halfs
  __shared__ uint4 wcs[256];    // w_corr fp16 [32][64]: 49 taps + bias at k=49 + zero pad

  const int tid = threadIdx.x;
  const int bx = blockIdx.x;
  const int p = bx >> 2, tile = bx & 3;
  const int y0 = (tile >> 1) * 16, x0 = (tile & 1) * 16;
  const int b = p >> 6, h = (p >> 3) & 7, t = p & 7;
  const int pk = (t < 7) ? p + 1 : p;
  const int ty = tid >> 4, tx = tid & 15;

  // stage w_corr (fp16, K padded to 64 with bias folded in at k=49)
  _Float16* wch = (_Float16*)wcs;
  for (int idx = tid; idx < 2048; idx += 256) {
    int d = idx >> 6, kk = idx & 63;
    float v = (kk < 49) ? wcorr[d * 49 + kk] : (kk == 49 ? bcorr[d] : 0.f);
    wch[idx] = (_Float16)v;
  }

  // stage k tile 22x22 vectors of 32 halfs (4 granules each), swizzled
  const _Float16* kbase = k16 + (size_t)pk * 32768;
#pragma unroll
  for (int i = 0; i < 8; ++i) {
    int g = tid + i * 256;
    if (g < 1936) {
      int vec = g >> 2, part = g & 3;
      int ky = vec / 22, kx = vec - ky * 22;
      int gy = y0 + ky - 3, gx = x0 + kx - 3;
      uint4 val = make_uint4(0u, 0u, 0u, 0u);
      if (gy >= 0 && gy < 32 && gx >= 0 && gx < 32)
        val = *(const uint4*)(kbase + ((size_t)gy * 32 + gx) * 32 + part * 8);
      int slot = (vec << 2) | (part ^ (vec & 3) ^ ((vec >> 2) & 3));
      smem[slot] = val;
    }
  }
  __syncthreads();

  // normalize k vectors in LDS
  for (int v = tid; v < 484; v += 256) {
    int base = v << 2;
    int sw = (v & 3) ^ ((v >> 2) & 3);
    uint4 gg[4];
#pragma unroll
    for (int pq = 0; pq < 4; ++pq) gg[pq] = smem[base | (pq ^ sw)];
    float ss = 0.f;
#pragma unroll
    for (int pq = 0; pq < 4; ++pq) {
      const unsigned* u = (const unsigned*)&gg[pq];
#pragma unroll
      for (int e = 0; e < 4; ++e) ss = dot2acc(u[e], u[e], ss);
    }
    float sc = 1.f / fmaxf(sqrtf(ss), 1e-12f);
#pragma unroll
    for (int pq = 0; pq < 4; ++pq) {
      unsigned* u = (unsigned*)&gg[pq];
#pragma unroll
      for (int e = 0; e < 4; ++e) u[e] = hscale(u[e], sc);
      smem[base | (pq ^ sw)] = gg[pq];
    }
  }
  __syncthreads();

  // per-thread q vector: load, normalize in-register (fp16)
  const _Float16* qptr = q16 + (size_t)p * 32768 + ((size_t)(y0 + ty) * 32 + (x0 + tx)) * 32;
  uint4 qv[4];
#pragma unroll
  for (int i = 0; i < 4; ++i) qv[i] = *(const uint4*)(qptr + i * 8);
  unsigned* qu = (unsigned*)qv;
  float qss = 0.f;
#pragma unroll
  for (int e = 0; e < 16; ++e) qss = dot2acc(qu[e], qu[e], qss);
  float qsc = 1.f / fmaxf(sqrtf(qss), 1e-12f);
#pragma unroll
  for (int e = 0; e < 16; ++e) qu[e] = hscale(qu[e], qsc);

  // 49 correlations via v_dot2_f32_f16
  float corr[49];
#pragma unroll
  for (int dy = 0; dy < 7; ++dy) {
#pragma unroll
    for (int dx = 0; dx < 7; ++dx) {
      int vec = (ty + dy) * 22 + (tx + dx);
      int base = vec << 2;
      int sw = (vec & 3) ^ ((vec >> 2) & 3);
      float c = 0.f;
#pragma unroll
      for (int pq = 0; pq < 4; ++pq) {
        uint4 kk = smem[base | (pq ^ sw)];
        const unsigned* ku = (const unsigned*)&kk;
#pragma unroll
        for (int e = 0; e < 4; ++e) c = dot2acc(qu[pq * 4 + e], ku[e], c);
      }
      corr[dy * 7 + dx] = c;
    }
  }
  __syncthreads();  // all k-tile reads done; smem reused as corr matrix

  // write corr row (pos = tid) as fp16: 49 taps, 1.0 at k=49 (bias), zeros to 63.
#pragma unroll
  for (int i = 0; i < 8; ++i) {
    uint4 val;
    unsigned* vu = (unsigned*)&val;
#pragma unroll
    for (int e = 0; e < 4; ++e) {
      int idx = i * 8 + e * 2;
      half2v hh;
      hh[0] = (_Float16)(idx < 49 ? corr[idx] : (idx == 49 ? 1.f : 0.f));
      hh[1] = (_Float16)(idx + 1 < 49 ? corr[idx + 1] : (idx + 1 == 49 ? 1.f : 0.f));
      vu[e] = __builtin_bit_cast(unsigned, hh);
    }
    smem[tid * 9 + i] = val;
  }
  __syncthreads();

  // MFMA: (256 pos x 64k) @ (64k x 32d): wave w handles m-tiles 4w..4w+3, 2 n-tiles
  _Float16* corrm = (_Float16*)smem;
  const int lane = tid & 63, w = tid >> 6;
  const int ml = lane & 15, qd = lane >> 4;
  float4v vacc[4][2];
  float4v z = {0.f, 0.f, 0.f, 0.f};
#pragma unroll
  for (int im = 0; im < 4; ++im) { vacc[im][0] = z; vacc[im][1] = z; }
#pragma unroll
  for (int ks = 0; ks < 2; ++ks) {
    half8 bfrag[2];
#pragma unroll
    for (int nt = 0; nt < 2; ++nt)
      bfrag[nt] = *(const half8*)(wch + (nt * 16 + ml) * 64 + ks * 32 + qd * 8);
#pragma unroll
    for (int im = 0; im < 4; ++im) {
      half8 afrag = *(const half8*)(corrm + (w * 64 + im * 16 + ml) * 72 + ks * 32 + qd * 8);
#pragma unroll
      for (int nt = 0; nt < 2; ++nt)
        vacc[im][nt] = __builtin_amdgcn_mfma_f32_16x16x32_f16(afrag, bfrag[nt], vacc[im][nt], 0, 0, 0);
    }
  }

  // epilogue: v -> outpre[b, n, h*32+d] fp16 (bias already folded via K=49 column)
#pragma unroll
  for (int im = 0; im < 4; ++im) {
#pragma unroll
    for (int nt = 0; nt < 2; ++nt) {
      int d = nt * 16 + ml;
#pragma unroll
      for (int r = 0; r < 4; ++r) {
        int pos = w * 64 + im * 16 + qd * 4 + r;
        int py = pos >> 4, px = pos & 15;
        int n = t * 1024 + (y0 + py) * 32 + (x0 + px);
        outp[(((size_t)b * 8192 + n) << 8) + h * 32 + d] = (_Float16)vacc[im][nt][r];
      }
    }
  }
}

// ---- proj GEMM: out = op16 @ wproj16^T + b_proj (fp32 out), 2-phase pipelined,
// swapped-operand MFMA -> float4 epilogue stores.
__global__ __launch_bounds__(256, 2)
void gemm_proj(const _Float16* __restrict__ A, const _Float16* __restrict__ Bw,
               const float* __restrict__ bp, float* __restrict__ out) {
  __shared__ _Float16 Ash[8192];
  __shared__ _Float16 Bsh[8192];
  const int tid = threadIdx.x;
  const int lane = tid & 63, w = tid >> 6;
  const int wm = w >> 1, wn = w & 1;
  const int ml = lane & 15, qd = lane >> 4;
  const int m0 = blockIdx.y * 128, n0 = blockIdx.x * 128;

  float4v acc[4][4];
  float4v z = {0.f, 0.f, 0.f, 0.f};
#pragma unroll
  for (int i = 0; i < 4; ++i)
#pragma unroll
    for (int j = 0; j < 4; ++j) acc[i][j] = z;

  const _Float16* Ap = A + (size_t)m0 * 256;
  const _Float16* Bp = Bw + (size_t)n0 * 256;
  const int gr = w * 64 + lane;
  const int row0 = gr >> 2, kb = gr & 3;

  {
    gload_lds16(Ap + row0 * 256 + kb * 8, Ash + (size_t)(w * 64) * 8);
    gload_lds16(Ap + (row0 + 64) * 256 + kb * 8, Ash + (size_t)(256 + w * 64) * 8);
    gload_lds16(Bp + row0 * 256 + kb * 8, Bsh + (size_t)(w * 64) * 8);
    gload_lds16(Bp + (row0 + 64) * 256 + kb * 8, Bsh + (size_t)(256 + w * 64) * 8);
  }
  __syncthreads();

#pragma unroll
  for (int kt = 0; kt < 8; ++kt) {
    const int cur = kt & 1;
    if (kt < 7) {
      const int k0 = (kt + 1) * 32;
      const int nb = (cur ^ 1) * 4096;
      gload_lds16(Ap + row0 * 256 + k0 + kb * 8, Ash + nb + (size_t)(w * 64) * 8);
      gload_lds16(Ap + (row0 + 64) * 256 + k0 + kb * 8, Ash + nb + (size_t)(256 + w * 64) * 8);
      gload_lds16(Bp + row0 * 256 + k0 + kb * 8, Bsh + nb + (size_t)(w * 64) * 8);
      gload_lds16(Bp + (row0 + 64) * 256 + k0 + kb * 8, Bsh + nb + (size_t)(256 + w * 64) * 8);
    }
    const _Float16* Ac = Ash + cur * 4096;
    const _Float16* Bc = Bsh + cur * 4096;
    half8 af[4], bf[4];
#pragma unroll
    for (int im = 0; im < 4; ++im) {
      af[im] = *(const half8*)(Ac + (wm * 64 + im * 16 + ml) * 32 + qd * 8);
      bf[im] = *(const half8*)(Bc + (wn * 64 + im * 16 + ml) * 32 + qd * 8);
    }
#pragma unroll
    for (int im = 0; im < 4; ++im)
#pragma unroll
      for (int in = 0; in < 4; ++in)
        acc[im][in] = __builtin_amdgcn_mfma_f32_16x16x32_f16(bf[in], af[im], acc[im][in], 0, 0, 0);
    __syncthreads();
  }

  // epilogue: lane covers row rowr, 4 consecutive cols -> one 16B store
#pragma unroll
  for (int im = 0; im < 4; ++im) {
    int rowr = m0 + wm * 64 + im * 16 + ml;
#pragma unroll
    for (int in = 0; in < 4; ++in) {
      int col = n0 + wn * 64 + in * 16 + qd * 4;
      float4 bb = *(const float4*)(bp + col);
      float4 o;
      o.x = acc[im][in][0] + bb.x;
      o.y = acc[im][in][1] + bb.y;
      o.z = acc[im][in][2] + bb.z;
      o.w = acc[im][in][3] + bb.w;
      *(float4*)(out + (size_t)rowr * 256 + col) = o;
    }
  }
}

extern "C" void kernel_launch(void* const* d_in, const int* in_sizes, int n_in,
                              void* d_out, int out_size, void* d_ws, size_t ws_size,
                              hipStream_t stream) {
  const float* x      = (const float*)d_in[0];
  const float* w_qk   = (const float*)d_in[1];
  const float* w_corr = (const float*)d_in[2];
  const float* b_corr = (const float*)d_in[3];
  const float* w_proj = (const float*)d_in[4];
  const float* b_proj = (const float*)d_in[5];
  float* out = (float*)d_out;

  char* ws = (char*)d_ws;
  _Float16* x16   = (_Float16*)(ws);
  _Float16* q16   = (_Float16*)(ws + 33554432);
  _Float16* k16   = (_Float16*)(ws + 67108864);
  _Float16* op16  = (_Float16*)(ws + 100663296);
  _Float16* wqk16 = (_Float16*)(ws + 134217728);
  _Float16* wpj16 = (_Float16*)(ws + 134479872);

  cvt_all<<<16576, 256, 0, stream>>>((const float4*)x, (const float4*)w_qk, (const float4*)w_proj,
                                     (ushort4*)x16, (ushort4*)wqk16, (ushort4*)wpj16);
  gemm_qk<<<dim3(4, 512), 256, 0, stream>>>(x16, wqk16, q16, k16);
  corr_kernel<<<2048, 256, 0, stream>>>(q16, k16, w_corr, b_corr, op16);
  gemm_proj<<<dim3(2, 512), 256, 0, stream>>>(op16, wpj16, b_proj, out);
}